// Round 2
// baseline (1077.158 us; speedup 1.0000x reference)
//
#include <hip/hip_runtime.h>
#include <stdint.h>

#define BB 64
#define TT 4096
#define DD 256
#define HH 341
#define NEGV (-1e9f)
#define TM 32     // rows of (b,t) per block in kernel 1
#define RBK 16    // rows per register accumulator tile

// ---------------------------------------------------------------- utilities

__device__ inline float gelu_exact(float x) {
  return 0.5f * x * (1.0f + erff(x * 0.70710678118654752440f));
}

__device__ inline uint32_t rotl32(uint32_t x, int d) { return (x << d) | (x >> (32 - d)); }

// JAX threefry2x32, jax_threefry_partitionable=True path (default in modern JAX):
// counter = 64-bit flat row-major index -> (hi=0, lo=j); key(42) -> (0, 42);
// 32-bit output = out0 ^ out1  (jax/_src/prng.py:_threefry_random_bits_partitionable).
// [If this still mismatches, the fallback theory is the legacy split-halves scheme,
//  which was tried in round 0 and failed.]
__device__ inline uint32_t threefry_bits(uint32_t j) {
  const uint32_t K0 = 0u, K1 = 42u;
  const uint32_t K2 = K0 ^ K1 ^ 0x1BD11BDAu;
  uint32_t x0 = 0u, x1 = j;        // (counts_hi, counts_lo)
  x0 += K0; x1 += K1;
#define TF_RND(r) { x0 += x1; x1 = rotl32(x1, r); x1 ^= x0; }
  TF_RND(13) TF_RND(15) TF_RND(26) TF_RND(6)
  x0 += K1; x1 += K2 + 1u;
  TF_RND(17) TF_RND(29) TF_RND(16) TF_RND(24)
  x0 += K2; x1 += K0 + 2u;
  TF_RND(13) TF_RND(15) TF_RND(26) TF_RND(6)
  x0 += K0; x1 += K1 + 3u;
  TF_RND(17) TF_RND(29) TF_RND(16) TF_RND(24)
  x0 += K1; x1 += K2 + 4u;
  TF_RND(13) TF_RND(15) TF_RND(26) TF_RND(6)
  x0 += K2; x1 += K0 + 5u;
#undef TF_RND
  return x0 ^ x1;                  // bits1 ^ bits2
}

__device__ inline float bred_sum(float v, volatile float* tmp, int tid) {
#pragma unroll
  for (int o = 32; o; o >>= 1) v += __shfl_xor(v, o, 64);
  __syncthreads();
  if ((tid & 63) == 0) tmp[tid >> 6] = v;
  __syncthreads();
  return tmp[0] + tmp[1] + tmp[2] + tmp[3];
}

__device__ inline float bred_max(float v, volatile float* tmp, int tid) {
#pragma unroll
  for (int o = 32; o; o >>= 1) v = fmaxf(v, __shfl_xor(v, o, 64));
  __syncthreads();
  if ((tid & 63) == 0) tmp[tid >> 6] = v;
  __syncthreads();
  return fmaxf(fmaxf(tmp[0], tmp[1]), fmaxf(tmp[2], tmp[3]));
}

__device__ inline int bred_sum_i(int v, volatile int* tmp, int tid) {
#pragma unroll
  for (int o = 32; o; o >>= 1) v += __shfl_xor(v, o, 64);
  __syncthreads();
  if ((tid & 63) == 0) tmp[tid >> 6] = v;
  __syncthreads();
  return tmp[0] + tmp[1] + tmp[2] + tmp[3];
}

// ------------------------------------------- kernel 1: mask+LN+MLP -> scores
// scores written to the "g" half of d_out (overwritten later by kernel 2).

__global__ __launch_bounds__(256) void k1_scores(
    const float* __restrict__ emb, const float* __restrict__ attn,
    const float* __restrict__ gamma, const float* __restrict__ beta,
    const float* __restrict__ W1, const float* __restrict__ b1,
    const float* __restrict__ W2, const float* __restrict__ b2,
    float* __restrict__ scores) {
  __shared__ float xn[TM * DD];       // 32 KB normalized activations
  __shared__ float red[RBK * 256];    // 16 KB score reduction
  __shared__ float mu_s[TM], rs_s[TM];

  const int bid = blockIdx.x;
  const int b = bid >> 7;             // T/TM = 128 tiles per batch row
  const int t0 = (bid & 127) * TM;
  const int tid = threadIdx.x;
  const int lane = tid & 63;
  const int wave = tid >> 6;

  const float* arow = attn + (size_t)b * TT + t0;
  float* srow = scores + (size_t)b * TT + t0;

  // attn is a prefix mask: if first row of tile masked, whole tile masked.
  if (arow[0] == 0.0f) {
    for (int i = tid; i < TM; i += 256) srow[i] = NEGV;
    return;
  }

  const float* ebase = emb + ((size_t)b * TT + t0) * DD;

  // stage emb*attn into LDS; per-row mean/var via wave shuffle reduce
  for (int r = wave; r < TM; r += 4) {
    float a = arow[r];
    float4 x4 = ((const float4*)(ebase + (size_t)r * DD))[lane];
    x4.x *= a; x4.y *= a; x4.z *= a; x4.w *= a;
    float s = x4.x + x4.y + x4.z + x4.w;
    float ss = x4.x * x4.x + x4.y * x4.y + x4.z * x4.z + x4.w * x4.w;
#pragma unroll
    for (int o = 32; o; o >>= 1) { s += __shfl_xor(s, o, 64); ss += __shfl_xor(ss, o, 64); }
    float mu = s * (1.0f / DD);
    float var = ss * (1.0f / DD) - mu * mu;
    if (lane == 0) { mu_s[r] = mu; rs_s[r] = 1.0f / sqrtf(var + 1e-5f); }
    ((float4*)(xn + r * DD))[lane] = x4;
  }
  __syncthreads();

  // normalize in place
  for (int i = tid; i < TM * DD / 4; i += 256) {
    int r = i >> 6;
    int c4 = i & 63;
    float4 xv = ((float4*)xn)[i];
    float4 gv = ((const float4*)gamma)[c4];
    float4 bv = ((const float4*)beta)[c4];
    float mu = mu_s[r], rs = rs_s[r];
    xv.x = (xv.x - mu) * rs * gv.x + bv.x;
    xv.y = (xv.y - mu) * rs * gv.y + bv.y;
    xv.z = (xv.z - mu) * rs * gv.z + bv.z;
    xv.w = (xv.w - mu) * rs * gv.w + bv.w;
    ((float4*)xn)[i] = xv;
  }
  __syncthreads();

  // each active thread owns h = 2*tid and 2*tid+1 (guarded for H=341 odd)
  const bool active = tid < 171;
  const int h0 = 2 * tid;
  const bool has2 = (h0 + 1) < HH;
  const int hB = has2 ? (h0 + 1) : h0;  // safe in-bounds column
  float w2c0 = 0.f, w2c1 = 0.f, bc0 = 0.f, bc1 = 0.f;
  if (active) {
    w2c0 = W2[h0];
    bc0 = b1[h0];
    w2c1 = has2 ? W2[hB] : 0.0f;        // zero kills duplicate column
    bc1 = b1[hB];
  }
  const float bias2 = b2[0];

  for (int rb = 0; rb < TM / RBK; ++rb) {
    float c[RBK];
#pragma unroll
    for (int r = 0; r < RBK; ++r) c[r] = 0.0f;
    if (active) {
      float acc0[RBK], acc1[RBK];
#pragma unroll
      for (int r = 0; r < RBK; ++r) { acc0[r] = 0.0f; acc1[r] = 0.0f; }
      const float* xb = xn + rb * RBK * DD;
      const float* wA = W1 + h0;
      const float* wBp = W1 + hB;
      for (int d = 0; d < DD; d += 4) {
        float wa0 = wA[(d + 0) * HH], wa1 = wA[(d + 1) * HH];
        float wa2 = wA[(d + 2) * HH], wa3 = wA[(d + 3) * HH];
        float wb0 = wBp[(d + 0) * HH], wb1 = wBp[(d + 1) * HH];
        float wb2 = wBp[(d + 2) * HH], wb3 = wBp[(d + 3) * HH];
#pragma unroll
        for (int r = 0; r < RBK; ++r) {
          float4 x = *(const float4*)(xb + r * DD + d);  // wave-uniform: LDS broadcast
          acc0[r] = fmaf(x.w, wa3, fmaf(x.z, wa2, fmaf(x.y, wa1, fmaf(x.x, wa0, acc0[r]))));
          acc1[r] = fmaf(x.w, wb3, fmaf(x.z, wb2, fmaf(x.y, wb1, fmaf(x.x, wb0, acc1[r]))));
        }
      }
#pragma unroll
      for (int r = 0; r < RBK; ++r) {
        c[r] = gelu_exact(acc0[r] + bc0) * w2c0 + gelu_exact(acc1[r] + bc1) * w2c1;
      }
    }
#pragma unroll
    for (int r = 0; r < RBK; ++r) red[r * 256 + tid] = c[r];
    __syncthreads();
#pragma unroll
    for (int s2 = 128; s2 >= 1; s2 >>= 1) {
      for (int i = tid; i < RBK * s2; i += 256) {
        int r = i / s2, j = i - r * s2;
        red[r * 256 + j] += red[r * 256 + j + s2];
      }
      __syncthreads();
    }
    if (tid < RBK) {
      int r = rb * RBK + tid;
      srow[r] = (arow[r] != 0.0f) ? (red[tid * 256] + bias2) : NEGV;
    }
    __syncthreads();
  }
}

// ---------------- kernel 2: per batch row — entmax15, gumbel top-k, z/g/tv

__global__ __launch_bounds__(256) void k2_select(
    const float* __restrict__ attn, float* __restrict__ out, float* __restrict__ row_tv) {
  __shared__ float gs[TT];   // g values for TV
  __shared__ float ftmp[4];
  __shared__ int itmp[4];

  const int b = blockIdx.x, tid = threadIdx.x;
  const float* arow = attn + (size_t)b * TT;
  float* zrow = out + (size_t)b * TT;
  float* grow = out + (size_t)BB * TT + (size_t)b * TT;  // holds scores right now

  float x_loc[16], a_loc[16];
  uint32_t key_loc[16];
  float cnt = 0.0f, mx = -3.4e38f;
#pragma unroll
  for (int i = 0; i < 16; ++i) {
    int t = tid + i * 256;
    float s = grow[t];          // masked scores (NEG at invalid)
    float a = arow[t];
    a_loc[i] = a;
    x_loc[i] = s;
    cnt += a;
    mx = fmaxf(mx, s);
    // gumbel = -log(-log(u + EPS) + EPS), u from threefry bits
    uint32_t bits = threefry_bits((uint32_t)(b * TT + t));
    float u = __uint_as_float(0x3F800000u | (bits >> 9)) - 1.0f;
    float gum = -logf(1e-6f - logf(u + 1e-6f));
    float pert = (a != 0.0f ? s : 0.0f) + gum;   // scores*attn + gumbel
    uint32_t fb = __float_as_uint(pert);
    uint32_t msk = ((int32_t)fb < 0) ? 0xFFFFFFFFu : 0x80000000u;
    key_loc[i] = fb ^ msk;      // order-preserving float->uint
  }
  float t_eff = bred_sum(cnt, ftmp, tid);
  mx = bred_max(mx, ftmp, tid);

  // entmax15: x = (s - max)/2 (TAU=1), solve sum relu(x-tau)^2 = 1 by bisection
#pragma unroll
  for (int i = 0; i < 16; ++i) x_loc[i] = (x_loc[i] - mx) * 0.5f;

  float lo = -1.0f, hi = 0.0f;
  for (int it = 0; it < 36; ++it) {
    float mid = 0.5f * (lo + hi);
    float p = 0.0f;
#pragma unroll
    for (int i = 0; i < 16; ++i) {
      float d = x_loc[i] - mid;
      if (d > 0.0f) p = fmaf(d, d, p);
    }
    float f = bred_sum(p, ftmp, tid);
    if (f >= 1.0f) lo = mid; else hi = mid;
  }
  const float tau = 0.5f * (lo + hi);

  // k = clip(round(0.3*t_eff), 1, max(t_eff,1)); rintf = round-half-even like jnp.round
  float kf = rintf(0.3f * t_eff);
  kf = fminf(fmaxf(kf, 1.0f), fmaxf(t_eff, 1.0f));
  int kk = (int)kf;

  // exact k-th largest of pert via MSB radix select on sortable keys
  uint32_t prefix = 0u;
  for (int bit = 31; bit >= 0; --bit) {
    uint32_t test = prefix | (1u << bit);
    uint32_t hi_test = test >> bit;
    int c = 0;
#pragma unroll
    for (int i = 0; i < 16; ++i) c += (int)((key_loc[i] >> bit) == hi_test);
    int ct = bred_sum_i(c, itmp, tid);
    if (ct >= kk) prefix = test; else kk -= ct;
  }
  const uint32_t thr = prefix;

#pragma unroll
  for (int i = 0; i < 16; ++i) {
    int t = tid + i * 256;
    float d = x_loc[i] - tau;
    float z = (d > 0.0f) ? d * d : 0.0f;
    z *= a_loc[i];
    float h = (key_loc[i] >= thr) ? a_loc[i] : 0.0f;  // (pert>=thr)*attn
    float g = (h - z) + z;                             // same fp32 ops as reference
    zrow[t] = z;
    gs[t] = g;
  }
  __syncthreads();

  float tvn = 0.0f, tvd = 0.0f;
#pragma unroll
  for (int i = 0; i < 16; ++i) {
    int t = tid + i * 256;
    grow[t] = gs[t];            // overwrite staged scores with final g
    if (t > 0) {
      float valid = arow[t] * arow[t - 1];
      tvn += fabsf(gs[t] - gs[t - 1]) * valid;
      tvd += valid;
    }
  }
  tvn = bred_sum(tvn, ftmp, tid);
  tvd = bred_sum(tvd, ftmp, tid);
  if (tid == 0) row_tv[b] = tvn / fmaxf(tvd, 1.0f);
}

// ------------------------------------------------- kernel 3: reg scalar

__global__ __launch_bounds__(64) void k3_final(const float* __restrict__ row_tv,
                                               float* __restrict__ out) {
  float v = row_tv[threadIdx.x];
#pragma unroll
  for (int o = 32; o; o >>= 1) v += __shfl_xor(v, o, 64);
  if (threadIdx.x == 0) out[2 * BB * TT] = 0.1f * (v * (1.0f / BB));
}

// -------------------------------------------------------------- launcher

extern "C" void kernel_launch(void* const* d_in, const int* in_sizes, int n_in,
                              void* d_out, int out_size, void* d_ws, size_t ws_size,
                              hipStream_t stream) {
  const float* emb   = (const float*)d_in[0];
  const float* attn  = (const float*)d_in[1];
  const float* gamma = (const float*)d_in[2];
  const float* beta  = (const float*)d_in[3];
  const float* W1    = (const float*)d_in[4];
  const float* b1    = (const float*)d_in[5];
  const float* W2    = (const float*)d_in[6];
  const float* b2    = (const float*)d_in[7];
  float* out = (float*)d_out;
  float* ws  = (float*)d_ws;   // 64 floats of row TV

  k1_scores<<<dim3(BB * TT / TM), dim3(256), 0, stream>>>(
      emb, attn, gamma, beta, W1, b1, W2, b2, out + (size_t)BB * TT);
  k2_select<<<dim3(BB), dim3(256), 0, stream>>>(attn, out, ws);
  k3_final<<<dim3(1), dim3(64), 0, stream>>>(ws, out);
}

// Round 3
// 693.880 us; speedup vs baseline: 1.5524x; 1.5524x over previous
//
#include <hip/hip_runtime.h>
#include <stdint.h>

#define BB 64
#define TT 4096
#define DD 256
#define HH 341
#define HP 384      // padded H: 24 tiles of 16
#define NEGV (-1e9f)

typedef __attribute__((ext_vector_type(8))) short short8;
typedef __attribute__((ext_vector_type(4))) float f32x4;

// ---------------------------------------------------------------- utilities

__device__ inline float gelu_exact(float x) {
  return 0.5f * x * (1.0f + erff(x * 0.70710678118654752440f));
}

__device__ inline uint32_t rotl32(uint32_t x, int d) { return (x << d) | (x >> (32 - d)); }

// JAX threefry2x32, jax_threefry_partitionable=True (verified passing in R1):
// counter = (hi=0, lo=j); key(42) -> (0,42); output = x0 ^ x1.
__device__ inline uint32_t threefry_bits(uint32_t j) {
  const uint32_t K0 = 0u, K1 = 42u;
  const uint32_t K2 = K0 ^ K1 ^ 0x1BD11BDAu;
  uint32_t x0 = 0u, x1 = j;
  x0 += K0; x1 += K1;
#define TF_RND(r) { x0 += x1; x1 = rotl32(x1, r); x1 ^= x0; }
  TF_RND(13) TF_RND(15) TF_RND(26) TF_RND(6)
  x0 += K1; x1 += K2 + 1u;
  TF_RND(17) TF_RND(29) TF_RND(16) TF_RND(24)
  x0 += K2; x1 += K0 + 2u;
  TF_RND(13) TF_RND(15) TF_RND(26) TF_RND(6)
  x0 += K0; x1 += K1 + 3u;
  TF_RND(17) TF_RND(29) TF_RND(16) TF_RND(24)
  x0 += K1; x1 += K2 + 4u;
  TF_RND(13) TF_RND(15) TF_RND(26) TF_RND(6)
  x0 += K2; x1 += K0 + 5u;
#undef TF_RND
  return x0 ^ x1;
}

// round-to-nearest-even fp32 -> bf16 split: x = hi + lo (+ ~2^-17 residual)
__device__ inline void bf16split(float x, short& hi, short& lo) {
  uint32_t u = __float_as_uint(x);
  uint32_t h = (u + 0x7FFFu + ((u >> 16) & 1u)) >> 16;
  float rem = x - __uint_as_float(h << 16);
  uint32_t ur = __float_as_uint(rem);
  uint32_t l = (ur + 0x7FFFu + ((ur >> 16) & 1u)) >> 16;
  hi = (short)h; lo = (short)l;
}

__device__ inline float bred_sum(float v, volatile float* tmp, int tid) {
#pragma unroll
  for (int o = 32; o; o >>= 1) v += __shfl_xor(v, o, 64);
  __syncthreads();
  if ((tid & 63) == 0) tmp[tid >> 6] = v;
  __syncthreads();
  return tmp[0] + tmp[1] + tmp[2] + tmp[3];
}

__device__ inline float bred_max(float v, volatile float* tmp, int tid) {
#pragma unroll
  for (int o = 32; o; o >>= 1) v = fmaxf(v, __shfl_xor(v, o, 64));
  __syncthreads();
  if ((tid & 63) == 0) tmp[tid >> 6] = v;
  __syncthreads();
  return fmaxf(fmaxf(tmp[0], tmp[1]), fmaxf(tmp[2], tmp[3]));
}

__device__ inline int bred_sum_i(int v, volatile int* tmp, int tid) {
#pragma unroll
  for (int o = 32; o; o >>= 1) v += __shfl_xor(v, o, 64);
  __syncthreads();
  if ((tid & 63) == 0) tmp[tid >> 6] = v;
  __syncthreads();
  return tmp[0] + tmp[1] + tmp[2] + tmp[3];
}

// ------------------- kernel 0: transpose + bf16-split W1 -> W1T hi/lo in ws
// W1T layout: [HP][DD] bf16 row-major (h-major, k contiguous); h>=HH rows are 0.

__global__ __launch_bounds__(256) void k0_prep(const float* __restrict__ W1,
                                               short* __restrict__ Whi,
                                               short* __restrict__ Wlo) {
  int idx = blockIdx.x * 256 + threadIdx.x;   // < HP*DD
  int h = idx >> 8, k = idx & 255;
  float v = (h < HH) ? W1[k * HH + h] : 0.0f;
  short hi, lo;
  bf16split(v, hi, lo);
  Whi[idx] = hi;
  Wlo[idx] = lo;
}

// ------------------- kernel 1: mask+LN+split-bf16 MFMA MLP -> scores
// 64 rows/block. A (LN'd activations) stored in LDS in MFMA A-fragment order:
// slot(mt,k0,q,i) = mt*512 + k0*64 + q*16 + (i^k0)   (16B units, XOR de-bank)
// holds A[row=mt*16+i][k = k0*32 + q*8 + j], j=0..7.
// Waves own 6 h-tiles each (24 tiles of 16 = HP). No barrier in the K-loop.

__global__ __launch_bounds__(256, 2) void k1_mfma(
    const float* __restrict__ emb, const float* __restrict__ attn,
    const float* __restrict__ gamma, const float* __restrict__ beta,
    const short* __restrict__ Whi, const float* __restrict__ b1,
    const float* __restrict__ W2, const float* __restrict__ b2,
    float* __restrict__ scores) {
  __shared__ short Ahi[16384];   // 32 KB
  __shared__ short Alo[16384];   // 32 KB  (total 64 KB exactly)

  const int bid = blockIdx.x;
  const int b = bid >> 6;             // 64 row-tiles per batch row
  const int t0 = (bid & 63) * 64;
  const int tid = threadIdx.x;
  const int w = tid >> 6;             // wave id = M-tile owner in prologue
  const int lane = tid & 63;

  // prefix mask: first row masked -> whole 64-row tile masked
  if (attn[(size_t)b * TT + t0] == 0.0f) {
    if (tid < 64) scores[(size_t)b * TT + t0 + tid] = NEGV;
    return;
  }

  // ---------------- prologue: LN 2 rows per wave-iteration, write A frags
  {
    const int half = lane >> 5;        // which of the 2 rows
    const int g = lane & 31;           // 8-col group within row
    const int k0g = g >> 2, qg = g & 3;
    float gg[8], bb[8];
#pragma unroll
    for (int j = 0; j < 8; ++j) { gg[j] = gamma[g * 8 + j]; bb[j] = beta[g * 8 + j]; }

    for (int it = 0; it < 8; ++it) {
      const int il = w * 16 + it * 2 + half;         // local row 0..63
      const size_t rowoff = (size_t)b * TT + t0 + il;
      const float a = attn[rowoff];
      const float* ep = emb + rowoff * DD + g * 8;
      float x[8];
      {
        float4 xA = *(const float4*)ep;
        float4 xB = *(const float4*)(ep + 4);
        x[0] = xA.x * a; x[1] = xA.y * a; x[2] = xA.z * a; x[3] = xA.w * a;
        x[4] = xB.x * a; x[5] = xB.y * a; x[6] = xB.z * a; x[7] = xB.w * a;
      }
      float s = 0.f, ss = 0.f;
#pragma unroll
      for (int j = 0; j < 8; ++j) { s += x[j]; ss += x[j] * x[j]; }
#pragma unroll
      for (int o = 16; o; o >>= 1) { s += __shfl_xor(s, o, 32); ss += __shfl_xor(ss, o, 32); }
      const float mu = s * (1.0f / DD);
      const float rs = 1.0f / sqrtf(ss * (1.0f / DD) - mu * mu + 1e-5f);

      short8 h8, l8;
#pragma unroll
      for (int j = 0; j < 8; ++j) {
        float y = (x[j] - mu) * rs * gg[j] + bb[j];
        short hi, lo;
        bf16split(y, hi, lo);
        h8[j] = hi; l8[j] = lo;
      }
      const int i15 = it * 2 + half;   // il & 15
      const int slot = w * 512 + k0g * 64 + qg * 16 + (i15 ^ k0g);
      *(short8*)&Ahi[slot * 8] = h8;
      *(short8*)&Alo[slot * 8] = l8;
    }
  }
  __syncthreads();

  // ---------------- K-loop: wave w owns h-tiles {6w .. 6w+5}
  const int r = lane & 15, q = lane >> 4;
  f32x4 acc[6][4];
#pragma unroll
  for (int j = 0; j < 6; ++j)
#pragma unroll
    for (int mt = 0; mt < 4; ++mt) acc[j][mt] = (f32x4){0.f, 0.f, 0.f, 0.f};

  int hb[6];
#pragma unroll
  for (int j = 0; j < 6; ++j) hb[j] = ((w * 6 + j) * 16 + r) * 256 + q * 8;

  for (int k0 = 0; k0 < 8; ++k0) {
    short8 ahi[4], alo[4];
#pragma unroll
    for (int mt = 0; mt < 4; ++mt) {
      const int slot = mt * 512 + k0 * 64 + q * 16 + (r ^ k0);
      ahi[mt] = *(const short8*)&Ahi[slot * 8];
      alo[mt] = *(const short8*)&Alo[slot * 8];
    }
#pragma unroll
    for (int j = 0; j < 6; ++j) {
      const short* bp = Whi + hb[j] + k0 * 32;
      short8 bhi = *(const short8*)bp;
      short8 blo = *(const short8*)(bp + HP * DD);   // Wlo follows Whi
#pragma unroll
      for (int mt = 0; mt < 4; ++mt) {
        acc[j][mt] = __builtin_amdgcn_mfma_f32_16x16x32_bf16(ahi[mt], bhi, acc[j][mt], 0, 0, 0);
        acc[j][mt] = __builtin_amdgcn_mfma_f32_16x16x32_bf16(ahi[mt], blo, acc[j][mt], 0, 0, 0);
        acc[j][mt] = __builtin_amdgcn_mfma_f32_16x16x32_bf16(alo[mt], bhi, acc[j][mt], 0, 0, 0);
      }
    }
  }

  // ---------------- epilogue: gelu -> *W2 -> reduce over h
  // C/D layout: col(h within tile) = lane&15, row = q*4 + reg  [m89/m91]
  float sacc[4][4];
#pragma unroll
  for (int mt = 0; mt < 4; ++mt)
#pragma unroll
    for (int rr = 0; rr < 4; ++rr) sacc[mt][rr] = 0.f;

#pragma unroll
  for (int j = 0; j < 6; ++j) {
    const int h = (w * 6 + j) * 16 + r;
    const float w2v = (h < HH) ? W2[h] : 0.f;
    const float b1v = (h < HH) ? b1[h] : 0.f;
#pragma unroll
    for (int mt = 0; mt < 4; ++mt)
#pragma unroll
      for (int rr = 0; rr < 4; ++rr) {
        float v = gelu_exact(acc[j][mt][rr] + b1v) * w2v;
        v += __shfl_xor(v, 1, 64);
        v += __shfl_xor(v, 2, 64);
        v += __shfl_xor(v, 4, 64);
        v += __shfl_xor(v, 8, 64);
        sacc[mt][rr] += v;
      }
  }

  __syncthreads();                         // all waves done reading A from LDS
  float* sred = (float*)Ahi;               // overlap: 256 floats
  if (r == 0) {
#pragma unroll
    for (int mt = 0; mt < 4; ++mt)
#pragma unroll
      for (int rr = 0; rr < 4; ++rr)
        sred[w * 64 + mt * 16 + q * 4 + rr] = sacc[mt][rr];
  }
  __syncthreads();

  if (tid < 64) {
    float sc = sred[tid] + sred[64 + tid] + sred[128 + tid] + sred[192 + tid] + b2[0];
    float a = attn[(size_t)b * TT + t0 + tid];
    scores[(size_t)b * TT + t0 + tid] = (a != 0.f) ? sc : NEGV;
  }
}

// ---------------- kernel 2: per batch row — entmax15, gumbel top-k, z/g/tv
// (unchanged from R1 — proven correct)

__global__ __launch_bounds__(256) void k2_select(
    const float* __restrict__ attn, float* __restrict__ out, float* __restrict__ row_tv) {
  __shared__ float gs[TT];
  __shared__ float ftmp[4];
  __shared__ int itmp[4];

  const int b = blockIdx.x, tid = threadIdx.x;
  const float* arow = attn + (size_t)b * TT;
  float* zrow = out + (size_t)b * TT;
  float* grow = out + (size_t)BB * TT + (size_t)b * TT;  // holds scores right now

  float x_loc[16], a_loc[16];
  uint32_t key_loc[16];
  float cnt = 0.0f, mx = -3.4e38f;
#pragma unroll
  for (int i = 0; i < 16; ++i) {
    int t = tid + i * 256;
    float s = grow[t];
    float a = arow[t];
    a_loc[i] = a;
    x_loc[i] = s;
    cnt += a;
    mx = fmaxf(mx, s);
    uint32_t bits = threefry_bits((uint32_t)(b * TT + t));
    float u = __uint_as_float(0x3F800000u | (bits >> 9)) - 1.0f;
    float gum = -logf(1e-6f - logf(u + 1e-6f));
    float pert = (a != 0.0f ? s : 0.0f) + gum;
    uint32_t fb = __float_as_uint(pert);
    uint32_t msk = ((int32_t)fb < 0) ? 0xFFFFFFFFu : 0x80000000u;
    key_loc[i] = fb ^ msk;
  }
  float t_eff = bred_sum(cnt, ftmp, tid);
  mx = bred_max(mx, ftmp, tid);

#pragma unroll
  for (int i = 0; i < 16; ++i) x_loc[i] = (x_loc[i] - mx) * 0.5f;

  float lo = -1.0f, hi = 0.0f;
  for (int it = 0; it < 36; ++it) {
    float mid = 0.5f * (lo + hi);
    float p = 0.0f;
#pragma unroll
    for (int i = 0; i < 16; ++i) {
      float d = x_loc[i] - mid;
      if (d > 0.0f) p = fmaf(d, d, p);
    }
    float f = bred_sum(p, ftmp, tid);
    if (f >= 1.0f) lo = mid; else hi = mid;
  }
  const float tau = 0.5f * (lo + hi);

  float kf = rintf(0.3f * t_eff);
  kf = fminf(fmaxf(kf, 1.0f), fmaxf(t_eff, 1.0f));
  int kk = (int)kf;

  uint32_t prefix = 0u;
  for (int bit = 31; bit >= 0; --bit) {
    uint32_t test = prefix | (1u << bit);
    uint32_t hi_test = test >> bit;
    int c = 0;
#pragma unroll
    for (int i = 0; i < 16; ++i) c += (int)((key_loc[i] >> bit) == hi_test);
    int ct = bred_sum_i(c, itmp, tid);
    if (ct >= kk) prefix = test; else kk -= ct;
  }
  const uint32_t thr = prefix;

#pragma unroll
  for (int i = 0; i < 16; ++i) {
    int t = tid + i * 256;
    float d = x_loc[i] - tau;
    float z = (d > 0.0f) ? d * d : 0.0f;
    z *= a_loc[i];
    float h = (key_loc[i] >= thr) ? a_loc[i] : 0.0f;
    float g = (h - z) + z;
    zrow[t] = z;
    gs[t] = g;
  }
  __syncthreads();

  float tvn = 0.0f, tvd = 0.0f;
#pragma unroll
  for (int i = 0; i < 16; ++i) {
    int t = tid + i * 256;
    grow[t] = gs[t];
    if (t > 0) {
      float valid = arow[t] * arow[t - 1];
      tvn += fabsf(gs[t] - gs[t - 1]) * valid;
      tvd += valid;
    }
  }
  tvn = bred_sum(tvn, ftmp, tid);
  tvd = bred_sum(tvd, ftmp, tid);
  if (tid == 0) row_tv[b] = tvn / fmaxf(tvd, 1.0f);
}

// ------------------------------------------------- kernel 3: reg scalar

__global__ __launch_bounds__(64) void k3_final(const float* __restrict__ row_tv,
                                               float* __restrict__ out) {
  float v = row_tv[threadIdx.x];
#pragma unroll
  for (int o = 32; o; o >>= 1) v += __shfl_xor(v, o, 64);
  if (threadIdx.x == 0) out[2 * BB * TT] = 0.1f * (v * (1.0f / BB));
}

// -------------------------------------------------------------- launcher

extern "C" void kernel_launch(void* const* d_in, const int* in_sizes, int n_in,
                              void* d_out, int out_size, void* d_ws, size_t ws_size,
                              hipStream_t stream) {
  const float* emb   = (const float*)d_in[0];
  const float* attn  = (const float*)d_in[1];
  const float* gamma = (const float*)d_in[2];
  const float* beta  = (const float*)d_in[3];
  const float* W1    = (const float*)d_in[4];
  const float* b1    = (const float*)d_in[5];
  const float* W2    = (const float*)d_in[6];
  const float* b2    = (const float*)d_in[7];
  float* out = (float*)d_out;

  float* row_tv = (float*)d_ws;                        // 64 floats
  short* Whi = (short*)((char*)d_ws + 512);            // [HP*DD] bf16 hi
  short* Wlo = Whi + HP * DD;                          // [HP*DD] bf16 lo

  k0_prep<<<dim3(HP * DD / 256), dim3(256), 0, stream>>>(W1, Whi, Wlo);
  k1_mfma<<<dim3(BB * TT / 64), dim3(256), 0, stream>>>(
      emb, attn, gamma, beta, Whi, b1, W2, b2, out + (size_t)BB * TT);
  k2_select<<<dim3(BB), dim3(256), 0, stream>>>(attn, out, row_tv);
  k3_final<<<dim3(1), dim3(64), 0, stream>>>(row_tv, out);
}